// Round 1
// baseline (1067.536 us; speedup 1.0000x reference)
//
#include <hip/hip_runtime.h>

#define HF 256   // H*F
#define DK 64    // inner dim (D_IN for layer1, F for layer2)

__device__ __forceinline__ float lrelu(float v) { return v >= 0.f ? v : 0.2f * v; }

// ---------------- GEMM: Z = X @ W, fused el/er epilogue -------------------
// X: [N,64], W: [64,256], al/ar: [256], Z: [N,256], el/er: [N,4]
// 256 threads: thread t owns output column t; W column held in registers;
// x row read via block-uniform loads (scalarized by compiler).
__global__ __launch_bounds__(256) void k_gemm(
    const float* __restrict__ X, const float* __restrict__ W,
    const float* __restrict__ al, const float* __restrict__ ar,
    float* __restrict__ Z, float* __restrict__ el, float* __restrict__ er,
    int nNodes, int nodesPerBlock)
{
    int tid  = threadIdx.x;
    int lane = tid & 63, wid = tid >> 6;   // wid == head
    float wcol[DK];
#pragma unroll
    for (int k = 0; k < DK; ++k) wcol[k] = W[k * HF + tid];
    float alv = al[tid], arv = ar[tid];

    int n0 = blockIdx.x * nodesPerBlock;
    int n1 = n0 + nodesPerBlock; if (n1 > nNodes) n1 = nNodes;
    for (int n = n0; n < n1; ++n) {
        const float* xr = X + (size_t)n * DK;
        float a0 = 0.f, a1 = 0.f, a2 = 0.f, a3 = 0.f;
#pragma unroll
        for (int k = 0; k < DK; k += 4) {
            a0 = fmaf(xr[k + 0], wcol[k + 0], a0);
            a1 = fmaf(xr[k + 1], wcol[k + 1], a1);
            a2 = fmaf(xr[k + 2], wcol[k + 2], a2);
            a3 = fmaf(xr[k + 3], wcol[k + 3], a3);
        }
        float acc = (a0 + a1) + (a2 + a3);
        Z[(size_t)n * HF + tid] = acc;
        float p = acc * alv, q = acc * arv;
#pragma unroll
        for (int m = 1; m < 64; m <<= 1) {
            p += __shfl_xor(p, m, 64);
            q += __shfl_xor(q, m, 64);
        }
        if (lane == 0) { el[n * 4 + wid] = p; er[n * 4 + wid] = q; }
    }
}

// ---------------- CSR build -------------------
__global__ void k_hist(const int* __restrict__ dst, int* __restrict__ cnt, int E_) {
    int i = blockIdx.x * blockDim.x + threadIdx.x;
    if (i < E_) atomicAdd(&cnt[dst[i]], 1);
}

#define SC_VPT 8
#define SC_CHUNK 2048  // 256 threads * 8

__global__ __launch_bounds__(256) void k_chunk_sums(const int* __restrict__ cnt,
                                                    int* __restrict__ bsums, int n) {
    int tid = threadIdx.x;
    int base = blockIdx.x * SC_CHUNK + tid * SC_VPT;
    int s = 0;
#pragma unroll
    for (int i = 0; i < SC_VPT; ++i) { int idx = base + i; if (idx < n) s += cnt[idx]; }
    int lane = tid & 63, wid = tid >> 6;
#pragma unroll
    for (int m = 1; m < 64; m <<= 1) s += __shfl_xor(s, m, 64);
    __shared__ int sh[4];
    if (lane == 0) sh[wid] = s;
    __syncthreads();
    if (tid == 0) bsums[blockIdx.x] = sh[0] + sh[1] + sh[2] + sh[3];
}

__global__ void k_scan_mid(int* bsums, int nb) {
    if (threadIdx.x == 0 && blockIdx.x == 0) {
        int acc = 0;
        for (int i = 0; i < nb; ++i) { int v = bsums[i]; bsums[i] = acc; acc += v; }
    }
}

__global__ __launch_bounds__(256) void k_scan_write(const int* __restrict__ cnt,
                                                    const int* __restrict__ bsums,
                                                    int* __restrict__ offs, int n) {
    int tid = threadIdx.x;
    int base = blockIdx.x * SC_CHUNK + tid * SC_VPT;
    int v[SC_VPT]; int s = 0;
#pragma unroll
    for (int i = 0; i < SC_VPT; ++i) { int idx = base + i; v[i] = (idx < n) ? cnt[idx] : 0; s += v[i]; }
    int lane = tid & 63, wid = tid >> 6;
    int sc = s;
#pragma unroll
    for (int d = 1; d < 64; d <<= 1) { int t = __shfl_up(sc, d, 64); if (lane >= d) sc += t; }
    __shared__ int wsum[4];
    if (lane == 63) wsum[wid] = sc;
    __syncthreads();
    int wbase = 0;
    for (int i = 0; i < wid; ++i) wbase += wsum[i];
    int p = bsums[blockIdx.x] + wbase + (sc - s);  // exclusive prefix of first element
#pragma unroll
    for (int i = 0; i < SC_VPT; ++i) {
        int idx = base + i;
        if (idx < n) {
            offs[idx] = p; p += v[i];
            if (idx == n - 1) offs[n] = p;
        }
    }
}

__global__ void k_scatter(const int* __restrict__ src, const int* __restrict__ dst,
                          const int* __restrict__ offs, int* __restrict__ fill,
                          int* __restrict__ esrc, int E_) {
    int i = blockIdx.x * blockDim.x + threadIdx.x;
    if (i < E_) {
        int d = dst[i];
        int pos = offs[d] + atomicAdd(&fill[d], 1);
        esrc[pos] = src[i];
    }
}

// ---------------- per-node edge softmax: write per-edge weights [E,4] ------
// one wave per node (4 nodes per 256-thread block)
__global__ __launch_bounds__(256) void k_stats(
    const int* __restrict__ esrc, const int* __restrict__ offs,
    const float* __restrict__ el, const float* __restrict__ er,
    float* __restrict__ w, int nNodes)
{
    int lane = threadIdx.x & 63, wid = threadIdx.x >> 6;
    int n = blockIdx.x * 4 + wid;
    if (n >= nNodes) return;
    int s0 = offs[n], s1 = offs[n + 1];
    if (s0 == s1) return;
    float er0 = er[n * 4 + 0], er1 = er[n * 4 + 1], er2 = er[n * 4 + 2], er3 = er[n * 4 + 3];

    float m0 = -1e30f, m1 = -1e30f, m2 = -1e30f, m3 = -1e30f;
    for (int j = s0 + lane; j < s1; j += 64) {
        int s = esrc[j];
        float4 e4 = *reinterpret_cast<const float4*>(el + (size_t)s * 4);
        m0 = fmaxf(m0, lrelu(e4.x + er0));
        m1 = fmaxf(m1, lrelu(e4.y + er1));
        m2 = fmaxf(m2, lrelu(e4.z + er2));
        m3 = fmaxf(m3, lrelu(e4.w + er3));
    }
#pragma unroll
    for (int m = 1; m < 64; m <<= 1) {
        m0 = fmaxf(m0, __shfl_xor(m0, m, 64));
        m1 = fmaxf(m1, __shfl_xor(m1, m, 64));
        m2 = fmaxf(m2, __shfl_xor(m2, m, 64));
        m3 = fmaxf(m3, __shfl_xor(m3, m, 64));
    }
    float t0 = 0.f, t1 = 0.f, t2 = 0.f, t3 = 0.f;
    for (int j = s0 + lane; j < s1; j += 64) {
        int s = esrc[j];
        float4 e4 = *reinterpret_cast<const float4*>(el + (size_t)s * 4);
        t0 += expf(lrelu(e4.x + er0) - m0);
        t1 += expf(lrelu(e4.y + er1) - m1);
        t2 += expf(lrelu(e4.z + er2) - m2);
        t3 += expf(lrelu(e4.w + er3) - m3);
    }
#pragma unroll
    for (int m = 1; m < 64; m <<= 1) {
        t0 += __shfl_xor(t0, m, 64);
        t1 += __shfl_xor(t1, m, 64);
        t2 += __shfl_xor(t2, m, 64);
        t3 += __shfl_xor(t3, m, 64);
    }
    float i0 = 1.f / t0, i1 = 1.f / t1, i2 = 1.f / t2, i3 = 1.f / t3;
    for (int j = s0 + lane; j < s1; j += 64) {
        int s = esrc[j];
        float4 e4 = *reinterpret_cast<const float4*>(el + (size_t)s * 4);
        float4 wv;
        wv.x = expf(lrelu(e4.x + er0) - m0) * i0;
        wv.y = expf(lrelu(e4.y + er1) - m1) * i1;
        wv.z = expf(lrelu(e4.z + er2) - m2) * i2;
        wv.w = expf(lrelu(e4.w + er3) - m3) * i3;
        *reinterpret_cast<float4*>(w + (size_t)j * 4) = wv;
    }
}

// ---------------- aggregation: block per node, thread = h*64+f ------------
__global__ __launch_bounds__(256) void k_agg(
    const int* __restrict__ esrc, const int* __restrict__ offs,
    const float* __restrict__ w, const float* __restrict__ z,
    const float* __restrict__ b, float* __restrict__ out,
    int do_tanh)
{
    int n = blockIdx.x;
    int tid = threadIdx.x;
    int h = tid >> 6;
    int s0 = offs[n], s1 = offs[n + 1];
    float acc = 0.f;
    for (int j = s0; j < s1; ++j) {
        int s = esrc[j];                      // block-uniform
        float wt = w[(size_t)j * 4 + h];      // wave-uniform (broadcast)
        acc = fmaf(z[(size_t)s * HF + tid], wt, acc);
    }
    float v = acc + b[tid];
    if (do_tanh) v = tanhf(v);
    __shared__ float sh[256];
    sh[tid] = v;
    __syncthreads();
    if (tid < 64)
        out[(size_t)n * 64 + tid] =
            0.25f * (sh[tid] + sh[tid + 64] + sh[tid + 128] + sh[tid + 192]);
}

// ---------------- launch -------------------
extern "C" void kernel_launch(void* const* d_in, const int* in_sizes, int n_in,
                              void* d_out, int out_size, void* d_ws, size_t ws_size,
                              hipStream_t stream) {
    const float* x   = (const float*)d_in[0];
    const int*   src = (const int*)d_in[1];
    const int*   dst = (const int*)d_in[2];
    const float* W1  = (const float*)d_in[3];
    const float* al1 = (const float*)d_in[4];
    const float* ar1 = (const float*)d_in[5];
    const float* b1  = (const float*)d_in[6];
    const float* W2  = (const float*)d_in[7];
    const float* al2 = (const float*)d_in[8];
    const float* ar2 = (const float*)d_in[9];
    const float* b2  = (const float*)d_in[10];
    float* out = (float*)d_out;

    int N_ = in_sizes[0] / 64;
    int E_ = in_sizes[1];

    char* ws = (char*)d_ws;
    size_t off = 0;
    auto alloc = [&](size_t bytes) -> void* {
        void* p = ws + off;
        off = (off + bytes + 255) & ~(size_t)255;
        return p;
    };
    float* z    = (float*)alloc((size_t)N_ * HF * 4);
    float* el   = (float*)alloc((size_t)N_ * 4 * 4);
    float* er   = (float*)alloc((size_t)N_ * 4 * 4);
    float* h1   = (float*)alloc((size_t)N_ * 64 * 4);
    float* w    = (float*)alloc((size_t)E_ * 4 * 4);
    int*   cnt  = (int*)alloc((size_t)N_ * 4);
    int*   offs = (int*)alloc((size_t)(N_ + 1) * 4);
    int*   fill = (int*)alloc((size_t)N_ * 4);
    int*   esrc = (int*)alloc((size_t)E_ * 4);
    int*   bsums= (int*)alloc(4096);

    hipMemsetAsync(cnt, 0, (size_t)N_ * 4, stream);
    hipMemsetAsync(fill, 0, (size_t)N_ * 4, stream);

    // CSR build (reused by both layers)
    int eb = (E_ + 255) / 256;
    k_hist<<<eb, 256, 0, stream>>>(dst, cnt, E_);
    int nchunks = (N_ + SC_CHUNK - 1) / SC_CHUNK;
    k_chunk_sums<<<nchunks, 256, 0, stream>>>(cnt, bsums, N_);
    k_scan_mid<<<1, 64, 0, stream>>>(bsums, nchunks);
    k_scan_write<<<nchunks, 256, 0, stream>>>(cnt, bsums, offs, N_);
    k_scatter<<<eb, 256, 0, stream>>>(src, dst, offs, fill, esrc, E_);

    int gb = (N_ + 63) / 64;
    // layer 1
    k_gemm<<<gb, 256, 0, stream>>>(x, W1, al1, ar1, z, el, er, N_, 64);
    k_stats<<<(N_ + 3) / 4, 256, 0, stream>>>(esrc, offs, el, er, w, N_);
    k_agg<<<N_, 256, 0, stream>>>(esrc, offs, w, z, b1, h1, 1);
    // layer 2
    k_gemm<<<gb, 256, 0, stream>>>(h1, W2, al2, ar2, z, el, er, N_, 64);
    k_stats<<<(N_ + 3) / 4, 256, 0, stream>>>(esrc, offs, el, er, w, N_);
    k_agg<<<N_, 256, 0, stream>>>(esrc, offs, w, z, b2, out, 0);
}

// Round 2
// 748.096 us; speedup vs baseline: 1.4270x; 1.4270x over previous
//
#include <hip/hip_runtime.h>

__device__ __forceinline__ float lrelu(float v) { return v >= 0.f ? v : 0.2f * v; }

// ---------------- prep: A_l[k][h] = sum_f W[k][h*64+f]*al[h][f] ------------
// one block, 256 threads; t -> (k = t>>2, h = t&3)
__global__ __launch_bounds__(256) void k_prep(
    const float* __restrict__ W, const float* __restrict__ al,
    const float* __restrict__ ar, float* __restrict__ Al, float* __restrict__ Ar)
{
    int t = threadIdx.x;
    int k = t >> 2, h = t & 3;
    float sl = 0.f, sr = 0.f;
#pragma unroll 8
    for (int f = 0; f < 64; ++f) {
        float wv = W[k * 256 + h * 64 + f];
        sl = fmaf(wv, al[h * 64 + f], sl);
        sr = fmaf(wv, ar[h * 64 + f], sr);
    }
    Al[k * 4 + h] = sl;
    Ar[k * 4 + h] = sr;
}

// ---------------- el/er = X @ [Al|Ar] : wave per node ----------------------
__global__ __launch_bounds__(256) void k_elr(
    const float* __restrict__ X, const float* __restrict__ Al,
    const float* __restrict__ Ar, float* __restrict__ el, float* __restrict__ er,
    int nNodes)
{
    int lane = threadIdx.x & 63, wid = threadIdx.x >> 6;
    int n = blockIdx.x * 4 + wid;
    if (n >= nNodes) return;
    float xv = X[(size_t)n * 64 + lane];
    float4 a = *reinterpret_cast<const float4*>(Al + lane * 4);
    float4 r = *reinterpret_cast<const float4*>(Ar + lane * 4);
    float p0 = xv * a.x, p1 = xv * a.y, p2 = xv * a.z, p3 = xv * a.w;
    float q0 = xv * r.x, q1 = xv * r.y, q2 = xv * r.z, q3 = xv * r.w;
#pragma unroll
    for (int m = 1; m < 64; m <<= 1) {
        p0 += __shfl_xor(p0, m, 64); p1 += __shfl_xor(p1, m, 64);
        p2 += __shfl_xor(p2, m, 64); p3 += __shfl_xor(p3, m, 64);
        q0 += __shfl_xor(q0, m, 64); q1 += __shfl_xor(q1, m, 64);
        q2 += __shfl_xor(q2, m, 64); q3 += __shfl_xor(q3, m, 64);
    }
    if (lane == 0) {
        *reinterpret_cast<float4*>(el + (size_t)n * 4) = make_float4(p0, p1, p2, p3);
        *reinterpret_cast<float4*>(er + (size_t)n * 4) = make_float4(q0, q1, q2, q3);
    }
}

// ---------------- CSR build -------------------
__global__ void k_hist(const int* __restrict__ dst, int* __restrict__ cnt, int E_) {
    int i = blockIdx.x * blockDim.x + threadIdx.x;
    if (i < E_) atomicAdd(&cnt[dst[i]], 1);
}

#define SC_VPT 8
#define SC_CHUNK 2048  // 256 threads * 8

__global__ __launch_bounds__(256) void k_chunk_sums(const int* __restrict__ cnt,
                                                    int* __restrict__ bsums, int n) {
    int tid = threadIdx.x;
    int base = blockIdx.x * SC_CHUNK + tid * SC_VPT;
    int s = 0;
#pragma unroll
    for (int i = 0; i < SC_VPT; ++i) { int idx = base + i; if (idx < n) s += cnt[idx]; }
    int lane = tid & 63, wid = tid >> 6;
#pragma unroll
    for (int m = 1; m < 64; m <<= 1) s += __shfl_xor(s, m, 64);
    __shared__ int sh[4];
    if (lane == 0) sh[wid] = s;
    __syncthreads();
    if (tid == 0) bsums[blockIdx.x] = sh[0] + sh[1] + sh[2] + sh[3];
}

__global__ void k_scan_mid(int* bsums, int nb) {
    if (threadIdx.x == 0 && blockIdx.x == 0) {
        int acc = 0;
        for (int i = 0; i < nb; ++i) { int v = bsums[i]; bsums[i] = acc; acc += v; }
    }
}

__global__ __launch_bounds__(256) void k_scan_write(const int* __restrict__ cnt,
                                                    const int* __restrict__ bsums,
                                                    int* __restrict__ offs, int n) {
    int tid = threadIdx.x;
    int base = blockIdx.x * SC_CHUNK + tid * SC_VPT;
    int v[SC_VPT]; int s = 0;
#pragma unroll
    for (int i = 0; i < SC_VPT; ++i) { int idx = base + i; v[i] = (idx < n) ? cnt[idx] : 0; s += v[i]; }
    int lane = tid & 63, wid = tid >> 6;
    int sc = s;
#pragma unroll
    for (int d = 1; d < 64; d <<= 1) { int t = __shfl_up(sc, d, 64); if (lane >= d) sc += t; }
    __shared__ int wsum[4];
    if (lane == 63) wsum[wid] = sc;
    __syncthreads();
    int wbase = 0;
    for (int i = 0; i < wid; ++i) wbase += wsum[i];
    int p = bsums[blockIdx.x] + wbase + (sc - s);  // exclusive prefix of first element
#pragma unroll
    for (int i = 0; i < SC_VPT; ++i) {
        int idx = base + i;
        if (idx < n) {
            offs[idx] = p; p += v[i];
            if (idx == n - 1) offs[n] = p;
        }
    }
}

__global__ void k_scatter(const int* __restrict__ src, const int* __restrict__ dst,
                          const int* __restrict__ offs, int* __restrict__ fill,
                          int* __restrict__ esrc, int E_) {
    int i = blockIdx.x * blockDim.x + threadIdx.x;
    if (i < E_) {
        int d = dst[i];
        int pos = offs[d] + atomicAdd(&fill[d], 1);
        esrc[pos] = src[i];
    }
}

// ---------------- per-node edge softmax: per-edge weights [E,4] ------------
// one wave per node; first 64 edges cached in registers (covers ~all nodes)
__global__ __launch_bounds__(256) void k_stats(
    const int* __restrict__ esrc, const int* __restrict__ offs,
    const float* __restrict__ el, const float* __restrict__ er,
    float* __restrict__ w, int nNodes)
{
    int lane = threadIdx.x & 63, wid = threadIdx.x >> 6;
    int n = blockIdx.x * 4 + wid;
    if (n >= nNodes) return;
    int s0 = offs[n], s1 = offs[n + 1];
    if (s0 == s1) return;
    float4 erv = *reinterpret_cast<const float4*>(er + (size_t)n * 4);

    int j0 = s0 + lane;
    float e0 = -1e30f, e1 = -1e30f, e2 = -1e30f, e3 = -1e30f;
    if (j0 < s1) {
        int s = esrc[j0];
        float4 v = *reinterpret_cast<const float4*>(el + (size_t)s * 4);
        e0 = lrelu(v.x + erv.x); e1 = lrelu(v.y + erv.y);
        e2 = lrelu(v.z + erv.z); e3 = lrelu(v.w + erv.w);
    }
    float m0 = e0, m1 = e1, m2 = e2, m3 = e3;
    for (int j = j0 + 64; j < s1; j += 64) {   // rare (degree > 64)
        int s = esrc[j];
        float4 v = *reinterpret_cast<const float4*>(el + (size_t)s * 4);
        m0 = fmaxf(m0, lrelu(v.x + erv.x)); m1 = fmaxf(m1, lrelu(v.y + erv.y));
        m2 = fmaxf(m2, lrelu(v.z + erv.z)); m3 = fmaxf(m3, lrelu(v.w + erv.w));
    }
#pragma unroll
    for (int m = 1; m < 64; m <<= 1) {
        m0 = fmaxf(m0, __shfl_xor(m0, m, 64));
        m1 = fmaxf(m1, __shfl_xor(m1, m, 64));
        m2 = fmaxf(m2, __shfl_xor(m2, m, 64));
        m3 = fmaxf(m3, __shfl_xor(m3, m, 64));
    }
    float x0 = expf(e0 - m0), x1 = expf(e1 - m1), x2 = expf(e2 - m2), x3 = expf(e3 - m3);
    float t0 = x0, t1 = x1, t2 = x2, t3 = x3;
    for (int j = j0 + 64; j < s1; j += 64) {
        int s = esrc[j];
        float4 v = *reinterpret_cast<const float4*>(el + (size_t)s * 4);
        t0 += expf(lrelu(v.x + erv.x) - m0); t1 += expf(lrelu(v.y + erv.y) - m1);
        t2 += expf(lrelu(v.z + erv.z) - m2); t3 += expf(lrelu(v.w + erv.w) - m3);
    }
#pragma unroll
    for (int m = 1; m < 64; m <<= 1) {
        t0 += __shfl_xor(t0, m, 64); t1 += __shfl_xor(t1, m, 64);
        t2 += __shfl_xor(t2, m, 64); t3 += __shfl_xor(t3, m, 64);
    }
    float i0 = 1.f / t0, i1 = 1.f / t1, i2 = 1.f / t2, i3 = 1.f / t3;
    if (j0 < s1)
        *reinterpret_cast<float4*>(w + (size_t)j0 * 4) =
            make_float4(x0 * i0, x1 * i1, x2 * i2, x3 * i3);
    for (int j = j0 + 64; j < s1; j += 64) {
        int s = esrc[j];
        float4 v = *reinterpret_cast<const float4*>(el + (size_t)s * 4);
        *reinterpret_cast<float4*>(w + (size_t)j * 4) = make_float4(
            expf(lrelu(v.x + erv.x) - m0) * i0, expf(lrelu(v.y + erv.y) - m1) * i1,
            expf(lrelu(v.z + erv.z) - m2) * i2, expf(lrelu(v.w + erv.w) - m3) * i3);
    }
}

// ---------------- gather: agg[n][h][k] = sum_j alpha_jh * X[s_j][k] --------
// wave per node, lane = k; 4 head accumulators per lane
__global__ __launch_bounds__(256) void k_gather(
    const int* __restrict__ esrc, const int* __restrict__ offs,
    const float* __restrict__ w, const float* __restrict__ X,
    float* __restrict__ agg, int nNodes)
{
    int lane = threadIdx.x & 63, wid = threadIdx.x >> 6;
    int n = blockIdx.x * 4 + wid;
    if (n >= nNodes) return;
    int s0 = offs[n], s1 = offs[n + 1];
    float a0 = 0.f, a1 = 0.f, a2 = 0.f, a3 = 0.f;
#pragma unroll 2
    for (int j = s0; j < s1; ++j) {
        int s = esrc[j];
        float4 wv = *reinterpret_cast<const float4*>(w + (size_t)j * 4);
        float xv = X[(size_t)s * 64 + lane];
        a0 = fmaf(xv, wv.x, a0); a1 = fmaf(xv, wv.y, a1);
        a2 = fmaf(xv, wv.z, a2); a3 = fmaf(xv, wv.w, a3);
    }
    float* ap = agg + (size_t)n * 256 + lane;
    ap[0] = a0; ap[64] = a1; ap[128] = a2; ap[192] = a3;
}

// ---------------- proj: out[n][h][f] = agg[n][h][:] . W[:,h*64+f] ----------
// + bias, optional tanh, head-mean. thread t = (h,f); W column in 64 VGPRs.
__global__ __launch_bounds__(256) void k_proj(
    const float* __restrict__ agg, const float* __restrict__ W,
    const float* __restrict__ B, float* __restrict__ out,
    int nNodes, int nodesPerBlock, int do_tanh)
{
    int tid = threadIdx.x;
    int h = tid >> 6;
    int hb = __builtin_amdgcn_readfirstlane(h);
    float wcol[64];
#pragma unroll
    for (int k = 0; k < 64; ++k) wcol[k] = W[k * 256 + tid];
    float bv = B[tid];

    __shared__ float sh[256];
    int n0 = blockIdx.x * nodesPerBlock;
    int n1 = n0 + nodesPerBlock; if (n1 > nNodes) n1 = nNodes;
    for (int n = n0; n < n1; ++n) {
        const float* xr = agg + (size_t)n * 256 + hb * 64;
        float a0 = 0.f, a1 = 0.f, a2 = 0.f, a3 = 0.f;
#pragma unroll
        for (int k = 0; k < 64; k += 4) {
            a0 = fmaf(xr[k + 0], wcol[k + 0], a0);
            a1 = fmaf(xr[k + 1], wcol[k + 1], a1);
            a2 = fmaf(xr[k + 2], wcol[k + 2], a2);
            a3 = fmaf(xr[k + 3], wcol[k + 3], a3);
        }
        float v = (a0 + a1) + (a2 + a3) + bv;
        if (do_tanh) v = tanhf(v);
        sh[tid] = v;
        __syncthreads();
        if (tid < 64)
            out[(size_t)n * 64 + tid] =
                0.25f * (sh[tid] + sh[tid + 64] + sh[tid + 128] + sh[tid + 192]);
        __syncthreads();
    }
}

// ---------------- launch -------------------
extern "C" void kernel_launch(void* const* d_in, const int* in_sizes, int n_in,
                              void* d_out, int out_size, void* d_ws, size_t ws_size,
                              hipStream_t stream) {
    const float* x   = (const float*)d_in[0];
    const int*   src = (const int*)d_in[1];
    const int*   dst = (const int*)d_in[2];
    const float* W1  = (const float*)d_in[3];
    const float* al1 = (const float*)d_in[4];
    const float* ar1 = (const float*)d_in[5];
    const float* b1  = (const float*)d_in[6];
    const float* W2  = (const float*)d_in[7];
    const float* al2 = (const float*)d_in[8];
    const float* ar2 = (const float*)d_in[9];
    const float* b2  = (const float*)d_in[10];
    float* out = (float*)d_out;

    int N_ = in_sizes[0] / 64;
    int E_ = in_sizes[1];

    char* ws = (char*)d_ws;
    size_t off = 0;
    auto alloc = [&](size_t bytes) -> void* {
        void* p = ws + off;
        off = (off + bytes + 255) & ~(size_t)255;
        return p;
    };
    float* agg  = (float*)alloc((size_t)N_ * 256 * 4);
    float* el   = (float*)alloc((size_t)N_ * 4 * 4);
    float* er   = (float*)alloc((size_t)N_ * 4 * 4);
    float* h1   = (float*)alloc((size_t)N_ * 64 * 4);
    float* w    = (float*)alloc((size_t)E_ * 4 * 4);
    int*   cnt  = (int*)alloc((size_t)N_ * 4);
    int*   offs = (int*)alloc((size_t)(N_ + 1) * 4);
    int*   fill = (int*)alloc((size_t)N_ * 4);
    int*   esrc = (int*)alloc((size_t)E_ * 4);
    int*   bsums= (int*)alloc(4096);
    float* A1l  = (float*)alloc(64 * 4 * 4);
    float* A1r  = (float*)alloc(64 * 4 * 4);
    float* A2l  = (float*)alloc(64 * 4 * 4);
    float* A2r  = (float*)alloc(64 * 4 * 4);

    hipMemsetAsync(cnt, 0, (size_t)N_ * 4, stream);
    hipMemsetAsync(fill, 0, (size_t)N_ * 4, stream);

    // attention-vector projections
    k_prep<<<1, 256, 0, stream>>>(W1, al1, ar1, A1l, A1r);
    k_prep<<<1, 256, 0, stream>>>(W2, al2, ar2, A2l, A2r);

    // CSR build (reused by both layers)
    int eb = (E_ + 255) / 256;
    k_hist<<<eb, 256, 0, stream>>>(dst, cnt, E_);
    int nchunks = (N_ + SC_CHUNK - 1) / SC_CHUNK;
    k_chunk_sums<<<nchunks, 256, 0, stream>>>(cnt, bsums, N_);
    k_scan_mid<<<1, 64, 0, stream>>>(bsums, nchunks);
    k_scan_write<<<nchunks, 256, 0, stream>>>(cnt, bsums, offs, N_);
    k_scatter<<<eb, 256, 0, stream>>>(src, dst, offs, fill, esrc, E_);

    int nb4 = (N_ + 3) / 4;
    int npb = 16, gproj = (N_ + npb - 1) / npb;
    // layer 1
    k_elr<<<nb4, 256, 0, stream>>>(x, A1l, A1r, el, er, N_);
    k_stats<<<nb4, 256, 0, stream>>>(esrc, offs, el, er, w, N_);
    k_gather<<<nb4, 256, 0, stream>>>(esrc, offs, w, x, agg, N_);
    k_proj<<<gproj, 256, 0, stream>>>(agg, W1, b1, h1, N_, npb, 1);
    // layer 2
    k_elr<<<nb4, 256, 0, stream>>>(h1, A2l, A2r, el, er, N_);
    k_stats<<<nb4, 256, 0, stream>>>(esrc, offs, el, er, w, N_);
    k_gather<<<nb4, 256, 0, stream>>>(esrc, offs, w, h1, agg, N_);
    k_proj<<<gproj, 256, 0, stream>>>(agg, W2, b2, out, N_, npb, 0);
}